// Round 7
// baseline (72.646 us; speedup 1.0000x reference)
//
#include <hip/hip_runtime.h>

#define BATCH 8
#define CH 64
#define CIN 3
#define HIN 224
#define WIN 224
#define KSZ 5
#define STRIDE 2
#define HO 110
#define WO 110
#define HW (HIN * WIN)

#define TPB 64                         // ONE wave per block -> zero barriers
#define RING 14                        // LDS ring rows per ci (1 step overwrite slack)
#define HALF_OUT 55                    // output rows per block (half plane)
#define NWG (BATCH * CH * 2)           // 1024 = 4 blocks/CU x 256 CU, one generation
#define LAST_IN 112                    // block-local input rows 0..112
#define NW 75

typedef float float4a __attribute__((ext_vector_type(4)));
typedef float float2a __attribute__((ext_vector_type(2)));

__device__ __forceinline__ void gload16(const float* src, float* ldsdst) {
    __builtin_amdgcn_global_load_lds(
        (const __attribute__((address_space(1))) void*)src,
        (__attribute__((address_space(3))) void*)ldsdst, 16, 0, 0);
}

__global__ __launch_bounds__(TPB) void conv5_wave_kernel(
    const float* __restrict__ x,
    const float* __restrict__ Wt,
    float* __restrict__ out)
{
    __shared__ float xs[CIN][RING][WIN];     // 37,632 B -> 4 blocks/CU

    // bijective XCD swizzle; both halves of a plane on one XCD
    const int wg  = blockIdx.x;
    const int swz = (wg & 7) * (NWG >> 3) + (wg >> 3);
    const int bc   = swz >> 1;
    const int half = swz & 1;
    const int c = bc & (CH - 1);
    const int l = threadIdx.x;               // lane 0..63

    const float* gplane = x + (size_t)bc * (CIN * HW) + (size_t)(half * 110) * WIN;

    // weights: wave-uniform address -> scalar loads, live in SGPRs
    float wr[NW];
#pragma unroll
    for (int i = 0; i < NW; ++i) wr[i] = Wt[c * NW + i];

    // ---- prologue: stage rows 0..9 x 3ci (30 DMAs, this wave only) ----
#pragma unroll
    for (int r = 0; r < 10; ++r) {
#pragma unroll
        for (int ci = 0; ci < CIN; ++ci) {
            if (l < 56) gload16(gplane + (size_t)ci * HW + (size_t)r * WIN + 4 * l,
                                &xs[ci][r][0]);
        }
    }

    int s0 = 0, sA = 10, sB = 11;            // rolling ring slots
    float* orow = out + (size_t)bc * (HO * WO) + (size_t)(half * HALF_OUT) * WO + 2 * l;

    for (int j = 0; j < HALF_OUT; ++j) {
        // ---- stage rows 2j+10, 2j+11 into slots of rows 2j-4, 2j-3 (dead) ----
        const int vA = 2 * j + 10, vB = 2 * j + 11;
        const int rA = vA > LAST_IN ? LAST_IN : vA;   // tail clamp -> dead slots
        const int rB = vB > LAST_IN ? LAST_IN : vB;

        asm volatile("s_waitcnt lgkmcnt(0)" ::: "memory");  // readers of dying slots drained
        __builtin_amdgcn_sched_barrier(0);
#pragma unroll
        for (int ci = 0; ci < CIN; ++ci) {
            if (l < 56) {
                gload16(gplane + (size_t)ci * HW + (size_t)rA * WIN + 4 * l, &xs[ci][sA][0]);
                gload16(gplane + (size_t)ci * HW + (size_t)rB * WIN + 4 * l, &xs[ci][sB][0]);
            }
        }
        // newest 20 vmem ops = stages j, j-1, j-2 (+2 stores) stay in flight;
        // guarantees stage <= j-3 (rows <= 2j+4) landed. Never vmcnt(0) in loop.
        asm volatile("s_waitcnt vmcnt(20)" ::: "memory");
        __builtin_amdgcn_sched_barrier(0);

        // ---- compute output row j from ring rows 2j..2j+4 ----
        if (l < 55) {
            float a0[CIN], a1[CIN];
#pragma unroll
            for (int ci = 0; ci < CIN; ++ci) { a0[ci] = 0.f; a1[ci] = 0.f; }
#pragma unroll
            for (int ci = 0; ci < CIN; ++ci) {
#pragma unroll
                for (int kh = 0; kh < KSZ; ++kh) {
                    int sk = s0 + kh; if (sk >= RING) sk -= RING;
                    const float* rp = &xs[ci][sk][4 * l];
                    float4a v0 = *(const float4a*)rp;        // floats 4l..4l+3 (16B stride: conflict-free)
                    float4a v1 = *(const float4a*)(rp + 4);  // floats 4l+4..4l+7
                    const float* w = wr + ci * 25 + kh * 5;
                    a0[ci] = fmaf(v0.x, w[0], a0[ci]);
                    a0[ci] = fmaf(v0.y, w[1], a0[ci]);
                    a0[ci] = fmaf(v0.z, w[2], a0[ci]);
                    a0[ci] = fmaf(v0.w, w[3], a0[ci]);
                    a0[ci] = fmaf(v1.x, w[4], a0[ci]);
                    a1[ci] = fmaf(v0.z, w[0], a1[ci]);
                    a1[ci] = fmaf(v0.w, w[1], a1[ci]);
                    a1[ci] = fmaf(v1.x, w[2], a1[ci]);
                    a1[ci] = fmaf(v1.y, w[3], a1[ci]);
                    a1[ci] = fmaf(v1.z, w[4], a1[ci]);
                }
            }
            float2a st = {(a0[0] + a0[1]) + a0[2], (a1[0] + a1[1]) + a1[2]};
            *(float2a*)(orow + (size_t)j * WO) = st;         // 110 contiguous floats/row
        }

        s0 += 2; if (s0 >= RING) s0 -= RING;
        sA += 2; if (sA >= RING) sA -= RING;
        sB += 2; if (sB >= RING) sB -= RING;
    }

    // drain DMA before LDS is reassigned to another block
    asm volatile("s_waitcnt vmcnt(0)" ::: "memory");
}

extern "C" void kernel_launch(void* const* d_in, const int* in_sizes, int n_in,
                              void* d_out, int out_size, void* d_ws, size_t ws_size,
                              hipStream_t stream)
{
    const float* x  = (const float*)d_in[0];
    const float* Wt = (const float*)d_in[1];
    float* out = (float*)d_out;

    conv5_wave_kernel<<<dim3(NWG), dim3(TPB), 0, stream>>>(x, Wt, out);
}

// Round 8
// 69.979 us; speedup vs baseline: 1.0381x; 1.0381x over previous
//
#include <hip/hip_runtime.h>

#define BATCH 8
#define CH 64
#define CIN 3
#define HIN 224
#define WIN 224
#define KSZ 5
#define STRIDE 2
#define HO 110
#define WO 110
#define HW (HIN * WIN)

#define TPB 64                         // ONE wave per block: no barriers at all
#define RING 14                        // ring rows per ci; overwrite hazard spans 2 steps
#define HALF_OUT 55                    // output rows per block (half plane)
#define NWG (BATCH * CH * 2)           // 1024 = 4 blocks/CU, one generation
#define LAST_IN 112
#define NW 75

typedef float float4a __attribute__((ext_vector_type(4)));
typedef float float2a __attribute__((ext_vector_type(2)));

__device__ __forceinline__ void gload16(const float* src, float* ldsdst) {
    __builtin_amdgcn_global_load_lds(
        (const __attribute__((address_space(1))) void*)src,
        (__attribute__((address_space(3))) void*)ldsdst, 16, 0, 0);
}

__global__ __launch_bounds__(TPB) void conv5_ring2_kernel(
    const float* __restrict__ x,
    const float* __restrict__ Wt,
    float* __restrict__ out)
{
    __shared__ float xs[CIN][RING][WIN];     // 37,632 B -> 4 blocks/CU

    const int wg  = blockIdx.x;
    const int swz = (wg & 7) * (NWG >> 3) + (wg >> 3);   // bijective XCD swizzle
    const int bc   = swz >> 1;
    const int half = swz & 1;
    const int c = bc & (CH - 1);
    const int l = threadIdx.x;

    const float* gplane = x + (size_t)bc * (CIN * HW) + (size_t)(half * 110) * WIN;

    // weights: wave-uniform -> scalar loads (SGPRs)
    float wr[NW];
#pragma unroll
    for (int i = 0; i < NW; ++i) wr[i] = Wt[c * NW + i];

    // ---- prologue: stage rows 0..9 x 3ci (30 DMAs) ----
#pragma unroll
    for (int r = 0; r < 10; ++r) {
#pragma unroll
        for (int ci = 0; ci < CIN; ++ci) {
            if (l < 56) gload16(gplane + (size_t)ci * HW + (size_t)r * WIN + 4 * l,
                                &xs[ci][r][0]);
        }
    }

    int s0 = 0, sA = 10, sB = 11;
    float* orow = out + (size_t)bc * (HO * WO) + (size_t)(half * HALF_OUT) * WO + 2 * l;

    for (int j = 0; j < HALF_OUT; ++j) {
        // stage rows 2j+10, 2j+11 into slots last READ at step j-2 (their readers
        // were consumed by step j-2's FMAs before its store -> already complete;
        // no lgkm drain needed)
        const int vA = 2 * j + 10, vB = 2 * j + 11;
        const int rA = vA > LAST_IN ? LAST_IN : vA;     // tail clamp -> dead slots
        const int rB = vB > LAST_IN ? LAST_IN : vB;
#pragma unroll
        for (int ci = 0; ci < CIN; ++ci) {
            if (l < 56) {
                gload16(gplane + (size_t)ci * HW + (size_t)rA * WIN + 4 * l, &xs[ci][sA][0]);
                gload16(gplane + (size_t)ci * HW + (size_t)rB * WIN + 4 * l, &xs[ci][sB][0]);
            }
        }
        // counted wait: newest 20 vmem ops (stages j..j-2 + 2 stores) stay in
        // flight; guarantees row 2j+4 (stage j-3, incl. store interleave: 4-slack)
        asm volatile("s_waitcnt vmcnt(20)" ::: "memory");

        // ---- compute output row j from ring rows 2j..2j+4 ----
        if (l < 55) {
            float a0[CIN], a1[CIN];
#pragma unroll
            for (int ci = 0; ci < CIN; ++ci) { a0[ci] = 0.f; a1[ci] = 0.f; }
#pragma unroll
            for (int ci = 0; ci < CIN; ++ci) {
#pragma unroll
                for (int kh = 0; kh < KSZ; ++kh) {
                    int sk = s0 + kh; if (sk >= RING) sk -= RING;
                    const float* rp = &xs[ci][sk][4 * l];
                    float4a v0 = *(const float4a*)rp;
                    float4a v1 = *(const float4a*)(rp + 4);
                    const float* w = wr + ci * 25 + kh * 5;
                    a0[ci] = fmaf(v0.x, w[0], a0[ci]);
                    a0[ci] = fmaf(v0.y, w[1], a0[ci]);
                    a0[ci] = fmaf(v0.z, w[2], a0[ci]);
                    a0[ci] = fmaf(v0.w, w[3], a0[ci]);
                    a0[ci] = fmaf(v1.x, w[4], a0[ci]);
                    a1[ci] = fmaf(v0.z, w[0], a1[ci]);
                    a1[ci] = fmaf(v0.w, w[1], a1[ci]);
                    a1[ci] = fmaf(v1.x, w[2], a1[ci]);
                    a1[ci] = fmaf(v1.y, w[3], a1[ci]);
                    a1[ci] = fmaf(v1.z, w[4], a1[ci]);
                }
            }
            float2a st = {(a0[0] + a0[1]) + a0[2], (a1[0] + a1[1]) + a1[2]};
            __builtin_nontemporal_store(st, (float2a*)(orow + (size_t)j * WO));
        }

        s0 += 2; if (s0 >= RING) s0 -= RING;
        sA += 2; if (sA >= RING) sA -= RING;
        sB += 2; if (sB >= RING) sB -= RING;
    }

    // drain DMA before LDS is reassigned to another block
    asm volatile("s_waitcnt vmcnt(0)" ::: "memory");
}

extern "C" void kernel_launch(void* const* d_in, const int* in_sizes, int n_in,
                              void* d_out, int out_size, void* d_ws, size_t ws_size,
                              hipStream_t stream)
{
    const float* x  = (const float*)d_in[0];
    const float* Wt = (const float*)d_in[1];
    float* out = (float*)d_out;

    conv5_ring2_kernel<<<dim3(NWG), dim3(TPB), 0, stream>>>(x, Wt, out);
}